// Round 16
// baseline (529.908 us; speedup 1.0000x reference)
//
#include <hip/hip_runtime.h>
#include <math.h>

#define HH 2048
#define WW 2048
#define NIMG 4
#define NCH 3
#define PLANES (NIMG*NCH)            // 12
#define PIX (HH*WW)                  // 4194304
#define TOT (PLANES*PIX)             // 50331648
#define W4 (WW/4)                    // 512
#define MED_RANK 25165823u           // floor(0.5*(TOT-1)), method='lower'

struct GW { float w[7]; };

// ---------------- module-global device state ----------------
// Radix split: 8 (top) / 12 (mid) / 12 (low). Lessons: (r3/r8) count, don't
// place; (r9) zero every LDS copy; (r10) >=8 loads in flight; (r6) no hot
// global addresses; (r12/r15) LDS b128 "conflicts" are largely inherent —
// occupancy, not padding, is the lever; (r15) 3-block/CU occupancy was the
// megakernel limiter.
#define H1C 64
#define H23C 16
__device__ unsigned g_hist1p[H1C * 256];
__device__ unsigned g_hist2p[H23C * 4096];
__device__ unsigned g_hist3p[H23C * 4096];
__device__ unsigned g_ctrl[8];       // [0]=b1 [1]=b2 [2]=b3 [3]=rank2 [4]=rank3
__device__ float    g_med;

__global__ void zero_state() {       // 256 blocks x 256
    int t = blockIdx.x * 256 + threadIdx.x;   // < 65536
    if (t < H1C * 256) g_hist1p[t] = 0;
    g_hist2p[t] = 0;
    g_hist3p[t] = 0;
    if (t < 8) g_ctrl[t] = 0;
    if (t == 0) g_med = 0.f;
}

// ---------------- Median helpers ----------------
__device__ __forceinline__ unsigned f2key(float f) {
    unsigned b = __float_as_uint(f);
    return (b & 0x80000000u) ? ~b : (b | 0x80000000u);
}

#define HCOPY 4
#define HSTRIDE 257

// Run-length histogram accumulator [r15]: one LDS atomic per bucket-run.
struct RLE {
    unsigned cur, cnt;
    __device__ __forceinline__ void init() { cur = 0xFFFFFFFFu; cnt = 0; }
    __device__ __forceinline__ void add(unsigned* myh, unsigned b) {
        if (b == cur) { cnt++; }
        else { if (cnt) atomicAdd(&myh[cur], cnt); cur = b; cnt = 1; }
    }
    __device__ __forceinline__ void flush(unsigned* myh) {
        if (cnt) atomicAdd(&myh[cur], cnt);
    }
};

// ---------------- Megakernel: Sobel + full 7x7 Gaussian + hist0 ------------
// Tile 32x32x3/block; 22.8 KB LDS (lh unioned into dead xs) -> ~7 blocks/CU.
#define TX 32
#define TY 32
__global__ __launch_bounds__(256) void sobel_gauss_full(const float* __restrict__ x,
                                                        float* __restrict__ S, GW g) {
    __shared__ float xs[40][40];        // image rows by-4..by+35; lh aliases this
    __shared__ float bh[3][38][36];     // Bh rows by-3..by+34, cols bx..bx+31
    unsigned* lh = (unsigned*)&xs[0][0];   // HCOPY*HSTRIDE = 1028 u32 <= 1600

    int bx = blockIdx.x * TX, by = blockIdx.y * TY;
    int n = blockIdx.z;
    const float* xp = x + (size_t)n * PIX;
    int t = threadIdx.x;

    // ---- stage x tile: 40 rows x 10 float4, zero-fill OOB ----
    for (int i = t; i < 40 * 10; i += 256) {
        int r = i / 10, cc = i % 10;
        int gr = by - 4 + r, gc = bx - 4 + cc * 4;
        float4 v = make_float4(0, 0, 0, 0);
        if (gr >= 0 && gr < HH && gc >= 0 && gc < WW)
            v = *(const float4*)(xp + (size_t)gr * WW + gc);
        *(float4*)&xs[r][cc * 4] = v;
    }
    __syncthreads();

    // ---- stage Bh: 38 rows x 8 col-groups, 3 channels ----
    for (int i = t; i < 38 * 8; i += 256) {
        int r = i >> 3, c = i & 7;
        int imgrow = by - 3 + r;
        if (imgrow < 0 || imgrow >= HH) {     // products zero-padded vertically
            float4 z = make_float4(0, 0, 0, 0);
            *(float4*)&bh[0][r][4 * c] = z;
            *(float4*)&bh[1][r][4 * c] = z;
            *(float4*)&bh[2][r][4 * c] = z;
            continue;
        }
        float r0[12], r1[12], r2[12];
#pragma unroll
        for (int b = 0; b < 3; b++) {
            float4 v0 = *(float4*)&xs[r][4 * c + 4 * b];
            float4 v1 = *(float4*)&xs[r + 1][4 * c + 4 * b];
            float4 v2 = *(float4*)&xs[r + 2][4 * c + 4 * b];
            r0[b*4+0]=v0.x; r0[b*4+1]=v0.y; r0[b*4+2]=v0.z; r0[b*4+3]=v0.w;
            r1[b*4+0]=v1.x; r1[b*4+1]=v1.y; r1[b*4+2]=v1.z; r1[b*4+3]=v1.w;
            r2[b*4+0]=v2.x; r2[b*4+1]=v2.y; r2[b*4+2]=v2.z; r2[b*4+3]=v2.w;
        }
        float pxx[10], pyy[10], pxy[10];
#pragma unroll
        for (int p = 0; p < 10; p++) {
            int ai = p + 1;
            int cg = bx + 4 * c - 3 + p;
            float Ix = (r0[ai+1] - r0[ai-1]) + 2.f*(r1[ai+1] - r1[ai-1]) + (r2[ai+1] - r2[ai-1]);
            float Iy = (r2[ai-1] - r0[ai-1]) + 2.f*(r2[ai]   - r0[ai])   + (r2[ai+1] - r0[ai+1]);
            bool ok = (cg >= 0 && cg < WW);
            pxx[p] = ok ? Ix * Ix : 0.f;
            pyy[p] = ok ? Iy * Iy : 0.f;
            pxy[p] = ok ? Ix * Iy : 0.f;
        }
        float4 oxx, oyy, oxy;
        float* ox = &oxx.x; float* oy = &oyy.x; float* oz = &oxy.x;
#pragma unroll
        for (int k = 0; k < 4; k++) {
            float sxx = 0.f, syy = 0.f, sxy = 0.f;
#pragma unroll
            for (int j = 0; j < 7; j++) {
                sxx += g.w[j] * pxx[k + j];
                syy += g.w[j] * pyy[k + j];
                sxy += g.w[j] * pxy[k + j];
            }
            ox[k] = sxx; oy[k] = syy; oz[k] = sxy;
        }
        *(float4*)&bh[0][r][4 * c] = oxx;
        *(float4*)&bh[1][r][4 * c] = oyy;
        *(float4*)&bh[2][r][4 * c] = oxy;
    }
    __syncthreads();

    // ---- xs now dead: zero lh (aliased) ----
    for (int i = t; i < HCOPY * HSTRIDE; i += 256) lh[i] = 0;
    __syncthreads();
    unsigned* myh = lh + (threadIdx.x & (HCOPY - 1)) * HSTRIDE;

    // ---- vertical 7-tap + S write + RLE hist: thread = 1 row x 4 cols ----
    int cg = t & 7, ro = t >> 3;              // ro in 0..31
    RLE rle; rle.init();
#pragma unroll
    for (int ch = 0; ch < 3; ch++) {
        float4 w[7];
#pragma unroll
        for (int j = 0; j < 7; j++) w[j] = *(float4*)&bh[ch][ro + j][4 * cg];
        float4 a0 = make_float4(0, 0, 0, 0);
#pragma unroll
        for (int j = 0; j < 7; j++) {
            float gw = g.w[j];
            a0.x += gw * w[j].x; a0.y += gw * w[j].y;
            a0.z += gw * w[j].z; a0.w += gw * w[j].w;
        }
        float* sp = S + (size_t)(n * NCH + ch) * PIX;
        *(float4*)(sp + (size_t)(by + ro) * WW + bx + 4 * cg) = a0;
        rle.add(myh, f2key(a0.x) >> 24); rle.add(myh, f2key(a0.y) >> 24);
        rle.add(myh, f2key(a0.z) >> 24); rle.add(myh, f2key(a0.w) >> 24);
    }
    rle.flush(myh);

    __syncthreads();
    if (threadIdx.x < 256) {
        unsigned v = 0;
#pragma unroll
        for (int c = 0; c < HCOPY; c++) v += lh[c * HSTRIDE + threadIdx.x];
        if (v) atomicAdd(&g_hist1p[((blockIdx.y * 64 + blockIdx.x) & (H1C - 1)) * 256 + threadIdx.x], v);
    }
}

// ---------------- Pass C: mid hist — single-iteration 8-load scan ----------
#define SCAN_BLOCKS 6144
#define NSTR 8
#define SLAB (TOT / 4 / NSTR)        // 1572864 float4; 6144*256 = SLAB exactly
__global__ __launch_bounds__(256) void hist_mid(const float* __restrict__ S) {
    __shared__ unsigned lh[4096];
    for (int i = threadIdx.x; i < 4096; i += 256) lh[i] = 0;
    __syncthreads();
    unsigned b1 = g_ctrl[0];
    const float4* S4 = (const float4*)S;
    long long i0 = (long long)blockIdx.x * 256 + threadIdx.x;
    float4 v[NSTR];
#pragma unroll
    for (int s = 0; s < NSTR; s++) v[s] = S4[i0 + (long long)s * SLAB];
#pragma unroll
    for (int s = 0; s < NSTR; s++) {
        unsigned k0 = f2key(v[s].x), k1 = f2key(v[s].y),
                 k2 = f2key(v[s].z), k3 = f2key(v[s].w);
        if ((k0 >> 24) == b1) atomicAdd(&lh[(k0 >> 12) & 0xFFFu], 1u);
        if ((k1 >> 24) == b1) atomicAdd(&lh[(k1 >> 12) & 0xFFFu], 1u);
        if ((k2 >> 24) == b1) atomicAdd(&lh[(k2 >> 12) & 0xFFFu], 1u);
        if ((k3 >> 24) == b1) atomicAdd(&lh[(k3 >> 12) & 0xFFFu], 1u);
    }
    __syncthreads();
    unsigned cpy = (blockIdx.x & (H23C - 1)) * 4096;
    for (int i = threadIdx.x; i < 4096; i += 256) {
        unsigned vv = lh[i];
        if (vv) atomicAdd(&g_hist2p[cpy + i], vv);
    }
}

// ---------------- Pass D: low hist — single-iteration 8-load scan ----------
__global__ __launch_bounds__(256) void hist_low(const float* __restrict__ S) {
    __shared__ unsigned lh[4096];
    for (int i = threadIdx.x; i < 4096; i += 256) lh[i] = 0;
    __syncthreads();
    unsigned p2 = (g_ctrl[0] << 12) | g_ctrl[1];
    const float4* S4 = (const float4*)S;
    long long i0 = (long long)blockIdx.x * 256 + threadIdx.x;
    float4 v[NSTR];
#pragma unroll
    for (int s = 0; s < NSTR; s++) v[s] = S4[i0 + (long long)s * SLAB];
#pragma unroll
    for (int s = 0; s < NSTR; s++) {
        unsigned k0 = f2key(v[s].x), k1 = f2key(v[s].y),
                 k2 = f2key(v[s].z), k3 = f2key(v[s].w);
        if ((k0 >> 12) == p2) atomicAdd(&lh[k0 & 0xFFFu], 1u);
        if ((k1 >> 12) == p2) atomicAdd(&lh[k1 & 0xFFFu], 1u);
        if ((k2 >> 12) == p2) atomicAdd(&lh[k2 & 0xFFFu], 1u);
        if ((k3 >> 12) == p2) atomicAdd(&lh[k3 & 0xFFFu], 1u);
    }
    __syncthreads();
    unsigned cpy = (blockIdx.x & (H23C - 1)) * 4096;
    for (int i = threadIdx.x; i < 4096; i += 256) {
        unsigned vv = lh[i];
        if (vv) atomicAdd(&g_hist3p[cpy + i], vv);
    }
}

// ---------------- bucket select over partial-copy histograms [r13-proven] --
__global__ __launch_bounds__(256) void select_k(int which) {
    __shared__ unsigned cnt[4096];
    __shared__ unsigned csum[256];
    int t = threadIdx.x;
    int nbins = (which == 0) ? 256 : 4096;
    if (which == 0) {
        unsigned s = 0;
        for (int c = 0; c < H1C; c++) s += g_hist1p[c * 256 + t];
        cnt[t] = s;
    } else {
        const unsigned* hp = (which == 1) ? g_hist2p : g_hist3p;
        for (int i = t; i < 4096; i += 256) {
            unsigned s = 0;
            for (int c = 0; c < H23C; c++) s += hp[c * 4096 + i];
            cnt[i] = s;
        }
    }
    __syncthreads();
    int per = nbins >> 8;
    unsigned s = 0;
    for (int j = 0; j < per; j++) s += cnt[t * per + j];
    csum[t] = s;
    __syncthreads();
    if (t == 0) {
        unsigned r = (which == 0) ? MED_RANK : (which == 1) ? g_ctrl[3] : g_ctrl[4];
        unsigned acc = 0; int c = 0;
        for (; c < 256; c++) { if (acc + csum[c] > r) break; acc += csum[c]; }
        int b = c * per;
        for (;; b++) { if (acc + cnt[b] > r) break; acc += cnt[b]; }
        if (which == 0)      { g_ctrl[0] = (unsigned)b; g_ctrl[3] = r - acc; }
        else if (which == 1) { g_ctrl[1] = (unsigned)b; g_ctrl[4] = r - acc; }
        else {
            g_ctrl[2] = (unsigned)b;
            unsigned key = (g_ctrl[0] << 24) | (g_ctrl[1] << 12) | (unsigned)b;
            unsigned bits = (key & 0x80000000u) ? (key ^ 0x80000000u) : ~key;
            g_med = __uint_as_float(bits);
        }
    }
}

// ---------------- Pass H: threshold + 7x7 NMS + mask — all-float4 [r13] ----
#define OX 64
#define OY 16
__global__ __launch_bounds__(256) void nms_kernel(const float* __restrict__ S,
                                                  float* __restrict__ out) {
    __shared__ float tin[22][72];
    __shared__ float hm[22][68];
    float med = g_med;
    int plane = blockIdx.z;
    int bx = blockIdx.x * OX, by = blockIdx.y * OY;
    const float* Sp = S + (size_t)plane * PIX;
    int t = threadIdx.x;

    for (int i = t; i < 22 * 18; i += 256) {
        int r = i / 18, cc = i % 18;
        int ghh = by + r - 3;
        int gc  = bx - 4 + cc * 4;
        float4 v = make_float4(-INFINITY, -INFINITY, -INFINITY, -INFINITY);
        if (ghh >= 0 && ghh < HH && gc >= 0 && gc < WW) {
            float4 s = *(const float4*)(Sp + (size_t)ghh * WW + gc);
            v.x = (s.x > med) ? s.x : 0.f;
            v.y = (s.y > med) ? s.y : 0.f;
            v.z = (s.z > med) ? s.z : 0.f;
            v.w = (s.w > med) ? s.w : 0.f;
        }
        *(float4*)&tin[r][cc * 4] = v;
    }
    __syncthreads();

    for (int i = t; i < 22 * 16; i += 256) {
        int r = i / 16, c = i % 16;
        float a0 = tin[r][4*c+1], a1 = tin[r][4*c+2], a2 = tin[r][4*c+3];
        float a3 = tin[r][4*c+4], a4 = tin[r][4*c+5], a5 = tin[r][4*c+6];
        float a6 = tin[r][4*c+7], a7 = tin[r][4*c+8], a8 = tin[r][4*c+9];
        float a9 = tin[r][4*c+10];
        float m03 = fmaxf(fmaxf(a0, a1), fmaxf(a2, a3));
        float m36 = fmaxf(fmaxf(a3, a4), fmaxf(a5, a6));
        float4 o;
        o.x = fmaxf(m03, fmaxf(fmaxf(a4, a5), a6));
        o.y = fmaxf(fmaxf(a1, a2), fmaxf(m36, a7));
        o.z = fmaxf(fmaxf(a2, a3), fmaxf(fmaxf(a4, m36), fmaxf(a7, a8)));
        o.w = fmaxf(m36, fmaxf(fmaxf(a7, a8), a9));
        *(float4*)&hm[r][4*c] = o;
    }
    __syncthreads();

    int cc = t & 15, ro = t >> 4;
    float4 m = *(const float4*)&hm[ro][4*cc];
#pragma unroll
    for (int d = 1; d < 7; d++) {
        float4 h = *(const float4*)&hm[ro + d][4*cc];
        m.x = fmaxf(m.x, h.x); m.y = fmaxf(m.y, h.y);
        m.z = fmaxf(m.z, h.z); m.w = fmaxf(m.w, h.w);
    }
    float4 c0 = *(const float4*)&tin[ro + 3][4*cc + 4];
    float4 o;
    o.x = (c0.x == m.x) ? c0.x : 0.f;
    o.y = (c0.y == m.y) ? c0.y : 0.f;
    o.z = (c0.z == m.z) ? c0.z : 0.f;
    o.w = (c0.w == m.w) ? c0.w : 0.f;
    *(float4*)(out + (size_t)plane * PIX + (size_t)(by + ro) * WW + bx + 4*cc) = o;
}

// ---------------- Launch ----------------
extern "C" void kernel_launch(void* const* d_in, const int* in_sizes, int n_in,
                              void* d_out, int out_size, void* d_ws, size_t ws_size,
                              hipStream_t stream) {
    const float* x = (const float*)d_in[0];
    float* O = (float*)d_out;
    float* W = (float*)d_ws;

    GW g;
    {
        double gg[7], s = 0.0;
        for (int i = 0; i < 7; i++) { double r = i - 3.0; gg[i] = exp(-r * r / 50.0); s += gg[i]; }
        for (int i = 0; i < 7; i++) g.w[i] = (float)(gg[i] / s);
    }

    zero_state<<<256, 256, 0, stream>>>();
    sobel_gauss_full<<<dim3(WW / TX, HH / TY, NIMG), 256, 0, stream>>>(x, W, g);
    select_k<<<1, 256, 0, stream>>>(0);
    hist_mid<<<SCAN_BLOCKS, 256, 0, stream>>>(W);
    select_k<<<1, 256, 0, stream>>>(1);
    hist_low<<<SCAN_BLOCKS, 256, 0, stream>>>(W);
    select_k<<<1, 256, 0, stream>>>(2);
    nms_kernel<<<dim3(WW / OX, HH / OY, PLANES), 256, 0, stream>>>(W, O);
}

// Round 18
// 497.249 us; speedup vs baseline: 1.0657x; 1.0657x over previous
//
#include <hip/hip_runtime.h>
#include <math.h>

#define HH 2048
#define WW 2048
#define NIMG 4
#define NCH 3
#define PLANES (NIMG*NCH)            // 12
#define PIX (HH*WW)                  // 4194304
#define TOT (PLANES*PIX)             // 50331648
#define W4 (WW/4)                    // 512
#define MED_RANK 25165823u           // floor(0.5*(TOT-1)), method='lower'

struct GW { float w[7]; };

// ---------------- module-global device state ----------------
// Radix split: 8 (top) / 12 (mid) / 12 (low). Lessons: (r3/r8) count, don't
// place; (r9) zero every LDS copy; (r10) >=8 loads in flight; (r6) no hot
// global addresses; (r12/r15) b128 LDS conflicts largely inherent; (r16)
// flush atomics scale with block count — keep scan grids at 2048, not 6144.
// (r17) identical source core-dumped in harness teardown — infra flake
// suspected; this is a byte-identical resubmission to test that.
#define H1C 64
#define H23C 16
__device__ unsigned g_hist1p[H1C * 256];
__device__ unsigned g_hist2p[H23C * 4096];
__device__ unsigned g_hist3p[H23C * 4096];
__device__ unsigned g_ctrl[8];       // [0]=b1 [1]=b2 [2]=b3 [3]=rank2 [4]=rank3
__device__ float    g_med;

__global__ void zero_state() {       // 256 blocks x 256
    int t = blockIdx.x * 256 + threadIdx.x;   // < 65536
    if (t < H1C * 256) g_hist1p[t] = 0;
    g_hist2p[t] = 0;
    g_hist3p[t] = 0;
    if (t < 8) g_ctrl[t] = 0;
    if (t == 0) g_med = 0.f;
}

// ---------------- Median helpers ----------------
__device__ __forceinline__ unsigned f2key(float f) {
    unsigned b = __float_as_uint(f);
    return (b & 0x80000000u) ? ~b : (b | 0x80000000u);
}

#define HCOPY 4
#define HSTRIDE 257

// Run-length histogram accumulator [r15]: one LDS atomic per bucket-run.
struct RLE {
    unsigned cur, cnt;
    __device__ __forceinline__ void init() { cur = 0xFFFFFFFFu; cnt = 0; }
    __device__ __forceinline__ void add(unsigned* myh, unsigned b) {
        if (b == cur) { cnt++; }
        else { if (cnt) atomicAdd(&myh[cur], cnt); cur = b; cnt = 1; }
    }
    __device__ __forceinline__ void flush(unsigned* myh) {
        if (cnt) atomicAdd(&myh[cur], cnt);
    }
};

// ---------------- Megakernel: Sobel + full 7x7 Gaussian + hist0 [r16] ------
// Tile 32x32x3/block; 22.8 KB LDS (lh unioned into dead xs) -> ~7 blocks/CU.
#define TX 32
#define TY 32
__global__ __launch_bounds__(256) void sobel_gauss_full(const float* __restrict__ x,
                                                        float* __restrict__ S, GW g) {
    __shared__ float xs[40][40];        // image rows by-4..by+35; lh aliases this
    __shared__ float bh[3][38][36];     // Bh rows by-3..by+34, cols bx..bx+31
    unsigned* lh = (unsigned*)&xs[0][0];   // HCOPY*HSTRIDE = 1028 u32 <= 1600

    int bx = blockIdx.x * TX, by = blockIdx.y * TY;
    int n = blockIdx.z;
    const float* xp = x + (size_t)n * PIX;
    int t = threadIdx.x;

    // ---- stage x tile: 40 rows x 10 float4, zero-fill OOB ----
    for (int i = t; i < 40 * 10; i += 256) {
        int r = i / 10, cc = i % 10;
        int gr = by - 4 + r, gc = bx - 4 + cc * 4;
        float4 v = make_float4(0, 0, 0, 0);
        if (gr >= 0 && gr < HH && gc >= 0 && gc < WW)
            v = *(const float4*)(xp + (size_t)gr * WW + gc);
        *(float4*)&xs[r][cc * 4] = v;
    }
    __syncthreads();

    // ---- stage Bh: 38 rows x 8 col-groups, 3 channels ----
    for (int i = t; i < 38 * 8; i += 256) {
        int r = i >> 3, c = i & 7;
        int imgrow = by - 3 + r;
        if (imgrow < 0 || imgrow >= HH) {     // products zero-padded vertically
            float4 z = make_float4(0, 0, 0, 0);
            *(float4*)&bh[0][r][4 * c] = z;
            *(float4*)&bh[1][r][4 * c] = z;
            *(float4*)&bh[2][r][4 * c] = z;
            continue;
        }
        float r0[12], r1[12], r2[12];
#pragma unroll
        for (int b = 0; b < 3; b++) {
            float4 v0 = *(float4*)&xs[r][4 * c + 4 * b];
            float4 v1 = *(float4*)&xs[r + 1][4 * c + 4 * b];
            float4 v2 = *(float4*)&xs[r + 2][4 * c + 4 * b];
            r0[b*4+0]=v0.x; r0[b*4+1]=v0.y; r0[b*4+2]=v0.z; r0[b*4+3]=v0.w;
            r1[b*4+0]=v1.x; r1[b*4+1]=v1.y; r1[b*4+2]=v1.z; r1[b*4+3]=v1.w;
            r2[b*4+0]=v2.x; r2[b*4+1]=v2.y; r2[b*4+2]=v2.z; r2[b*4+3]=v2.w;
        }
        float pxx[10], pyy[10], pxy[10];
#pragma unroll
        for (int p = 0; p < 10; p++) {
            int ai = p + 1;
            int cg = bx + 4 * c - 3 + p;
            float Ix = (r0[ai+1] - r0[ai-1]) + 2.f*(r1[ai+1] - r1[ai-1]) + (r2[ai+1] - r2[ai-1]);
            float Iy = (r2[ai-1] - r0[ai-1]) + 2.f*(r2[ai]   - r0[ai])   + (r2[ai+1] - r0[ai+1]);
            bool ok = (cg >= 0 && cg < WW);
            pxx[p] = ok ? Ix * Ix : 0.f;
            pyy[p] = ok ? Iy * Iy : 0.f;
            pxy[p] = ok ? Ix * Iy : 0.f;
        }
        float4 oxx, oyy, oxy;
        float* ox = &oxx.x; float* oy = &oyy.x; float* oz = &oxy.x;
#pragma unroll
        for (int k = 0; k < 4; k++) {
            float sxx = 0.f, syy = 0.f, sxy = 0.f;
#pragma unroll
            for (int j = 0; j < 7; j++) {
                sxx += g.w[j] * pxx[k + j];
                syy += g.w[j] * pyy[k + j];
                sxy += g.w[j] * pxy[k + j];
            }
            ox[k] = sxx; oy[k] = syy; oz[k] = sxy;
        }
        *(float4*)&bh[0][r][4 * c] = oxx;
        *(float4*)&bh[1][r][4 * c] = oyy;
        *(float4*)&bh[2][r][4 * c] = oxy;
    }
    __syncthreads();

    // ---- xs now dead: zero lh (aliased) ----
    for (int i = t; i < HCOPY * HSTRIDE; i += 256) lh[i] = 0;
    __syncthreads();
    unsigned* myh = lh + (threadIdx.x & (HCOPY - 1)) * HSTRIDE;

    // ---- vertical 7-tap + S write + RLE hist: thread = 1 row x 4 cols ----
    int cg = t & 7, ro = t >> 3;              // ro in 0..31
    RLE rle; rle.init();
#pragma unroll
    for (int ch = 0; ch < 3; ch++) {
        float4 w[7];
#pragma unroll
        for (int j = 0; j < 7; j++) w[j] = *(float4*)&bh[ch][ro + j][4 * cg];
        float4 a0 = make_float4(0, 0, 0, 0);
#pragma unroll
        for (int j = 0; j < 7; j++) {
            float gw = g.w[j];
            a0.x += gw * w[j].x; a0.y += gw * w[j].y;
            a0.z += gw * w[j].z; a0.w += gw * w[j].w;
        }
        float* sp = S + (size_t)(n * NCH + ch) * PIX;
        *(float4*)(sp + (size_t)(by + ro) * WW + bx + 4 * cg) = a0;
        rle.add(myh, f2key(a0.x) >> 24); rle.add(myh, f2key(a0.y) >> 24);
        rle.add(myh, f2key(a0.z) >> 24); rle.add(myh, f2key(a0.w) >> 24);
    }
    rle.flush(myh);

    __syncthreads();
    if (threadIdx.x < 256) {
        unsigned v = 0;
#pragma unroll
        for (int c = 0; c < HCOPY; c++) v += lh[c * HSTRIDE + threadIdx.x];
        if (v) atomicAdd(&g_hist1p[((blockIdx.y * 64 + blockIdx.x) & (H1C - 1)) * 256 + threadIdx.x], v);
    }
}

// ---------------- Pass C: mid hist — 2048-block, 24-load scan [r15] --------
#define SCAN_BLOCKS 2048
#define NSTR 8
#define SLAB (TOT / 4 / NSTR)        // 1572864 float4; 3 iters x 2048 x 256
__global__ __launch_bounds__(256) void hist_mid(const float* __restrict__ S) {
    __shared__ unsigned lh[4096];
    for (int i = threadIdx.x; i < 4096; i += 256) lh[i] = 0;
    __syncthreads();
    unsigned b1 = g_ctrl[0];
    const float4* S4 = (const float4*)S;
    long long i0 = (long long)blockIdx.x * 256 + threadIdx.x;
    const long long STRIDE = (long long)SCAN_BLOCKS * 256;  // 524288
    float4 v[3][NSTR];                 // 24 loads in flight
#pragma unroll
    for (int it = 0; it < 3; it++)
#pragma unroll
        for (int s = 0; s < NSTR; s++)
            v[it][s] = S4[i0 + it * STRIDE + (long long)s * SLAB];
#pragma unroll
    for (int it = 0; it < 3; it++)
#pragma unroll
        for (int s = 0; s < NSTR; s++) {
            unsigned k0 = f2key(v[it][s].x), k1 = f2key(v[it][s].y),
                     k2 = f2key(v[it][s].z), k3 = f2key(v[it][s].w);
            if ((k0 >> 24) == b1) atomicAdd(&lh[(k0 >> 12) & 0xFFFu], 1u);
            if ((k1 >> 24) == b1) atomicAdd(&lh[(k1 >> 12) & 0xFFFu], 1u);
            if ((k2 >> 24) == b1) atomicAdd(&lh[(k2 >> 12) & 0xFFFu], 1u);
            if ((k3 >> 24) == b1) atomicAdd(&lh[(k3 >> 12) & 0xFFFu], 1u);
        }
    __syncthreads();
    unsigned cpy = (blockIdx.x & (H23C - 1)) * 4096;
    for (int i = threadIdx.x; i < 4096; i += 256) {
        unsigned vv = lh[i];
        if (vv) atomicAdd(&g_hist2p[cpy + i], vv);
    }
}

// ---------------- Pass D: low hist — 2048-block, 24-load scan [r15] --------
__global__ __launch_bounds__(256) void hist_low(const float* __restrict__ S) {
    __shared__ unsigned lh[4096];
    for (int i = threadIdx.x; i < 4096; i += 256) lh[i] = 0;
    __syncthreads();
    unsigned p2 = (g_ctrl[0] << 12) | g_ctrl[1];
    const float4* S4 = (const float4*)S;
    long long i0 = (long long)blockIdx.x * 256 + threadIdx.x;
    const long long STRIDE = (long long)SCAN_BLOCKS * 256;
    float4 v[3][NSTR];
#pragma unroll
    for (int it = 0; it < 3; it++)
#pragma unroll
        for (int s = 0; s < NSTR; s++)
            v[it][s] = S4[i0 + it * STRIDE + (long long)s * SLAB];
#pragma unroll
    for (int it = 0; it < 3; it++)
#pragma unroll
        for (int s = 0; s < NSTR; s++) {
            unsigned k0 = f2key(v[it][s].x), k1 = f2key(v[it][s].y),
                     k2 = f2key(v[it][s].z), k3 = f2key(v[it][s].w);
            if ((k0 >> 12) == p2) atomicAdd(&lh[k0 & 0xFFFu], 1u);
            if ((k1 >> 12) == p2) atomicAdd(&lh[k1 & 0xFFFu], 1u);
            if ((k2 >> 12) == p2) atomicAdd(&lh[k2 & 0xFFFu], 1u);
            if ((k3 >> 12) == p2) atomicAdd(&lh[k3 & 0xFFFu], 1u);
        }
    __syncthreads();
    unsigned cpy = (blockIdx.x & (H23C - 1)) * 4096;
    for (int i = threadIdx.x; i < 4096; i += 256) {
        unsigned vv = lh[i];
        if (vv) atomicAdd(&g_hist3p[cpy + i], vv);
    }
}

// ---------------- bucket select over partial-copy histograms [r13-proven] --
__global__ __launch_bounds__(256) void select_k(int which) {
    __shared__ unsigned cnt[4096];
    __shared__ unsigned csum[256];
    int t = threadIdx.x;
    int nbins = (which == 0) ? 256 : 4096;
    if (which == 0) {
        unsigned s = 0;
        for (int c = 0; c < H1C; c++) s += g_hist1p[c * 256 + t];
        cnt[t] = s;
    } else {
        const unsigned* hp = (which == 1) ? g_hist2p : g_hist3p;
        for (int i = t; i < 4096; i += 256) {
            unsigned s = 0;
            for (int c = 0; c < H23C; c++) s += hp[c * 4096 + i];
            cnt[i] = s;
        }
    }
    __syncthreads();
    int per = nbins >> 8;
    unsigned s = 0;
    for (int j = 0; j < per; j++) s += cnt[t * per + j];
    csum[t] = s;
    __syncthreads();
    if (t == 0) {
        unsigned r = (which == 0) ? MED_RANK : (which == 1) ? g_ctrl[3] : g_ctrl[4];
        unsigned acc = 0; int c = 0;
        for (; c < 256; c++) { if (acc + csum[c] > r) break; acc += csum[c]; }
        int b = c * per;
        for (;; b++) { if (acc + cnt[b] > r) break; acc += cnt[b]; }
        if (which == 0)      { g_ctrl[0] = (unsigned)b; g_ctrl[3] = r - acc; }
        else if (which == 1) { g_ctrl[1] = (unsigned)b; g_ctrl[4] = r - acc; }
        else {
            g_ctrl[2] = (unsigned)b;
            unsigned key = (g_ctrl[0] << 24) | (g_ctrl[1] << 12) | (unsigned)b;
            unsigned bits = (key & 0x80000000u) ? (key ^ 0x80000000u) : ~key;
            g_med = __uint_as_float(bits);
        }
    }
}

// ---------------- Pass H: threshold + 7x7 NMS + mask — all-float4 [r13] ----
#define OX 64
#define OY 16
__global__ __launch_bounds__(256) void nms_kernel(const float* __restrict__ S,
                                                  float* __restrict__ out) {
    __shared__ float tin[22][72];
    __shared__ float hm[22][68];
    float med = g_med;
    int plane = blockIdx.z;
    int bx = blockIdx.x * OX, by = blockIdx.y * OY;
    const float* Sp = S + (size_t)plane * PIX;
    int t = threadIdx.x;

    for (int i = t; i < 22 * 18; i += 256) {
        int r = i / 18, cc = i % 18;
        int ghh = by + r - 3;
        int gc  = bx - 4 + cc * 4;
        float4 v = make_float4(-INFINITY, -INFINITY, -INFINITY, -INFINITY);
        if (ghh >= 0 && ghh < HH && gc >= 0 && gc < WW) {
            float4 s = *(const float4*)(Sp + (size_t)ghh * WW + gc);
            v.x = (s.x > med) ? s.x : 0.f;
            v.y = (s.y > med) ? s.y : 0.f;
            v.z = (s.z > med) ? s.z : 0.f;
            v.w = (s.w > med) ? s.w : 0.f;
        }
        *(float4*)&tin[r][cc * 4] = v;
    }
    __syncthreads();

    for (int i = t; i < 22 * 16; i += 256) {
        int r = i / 16, c = i % 16;
        float a0 = tin[r][4*c+1], a1 = tin[r][4*c+2], a2 = tin[r][4*c+3];
        float a3 = tin[r][4*c+4], a4 = tin[r][4*c+5], a5 = tin[r][4*c+6];
        float a6 = tin[r][4*c+7], a7 = tin[r][4*c+8], a8 = tin[r][4*c+9];
        float a9 = tin[r][4*c+10];
        float m03 = fmaxf(fmaxf(a0, a1), fmaxf(a2, a3));
        float m36 = fmaxf(fmaxf(a3, a4), fmaxf(a5, a6));
        float4 o;
        o.x = fmaxf(m03, fmaxf(fmaxf(a4, a5), a6));
        o.y = fmaxf(fmaxf(a1, a2), fmaxf(m36, a7));
        o.z = fmaxf(fmaxf(a2, a3), fmaxf(fmaxf(a4, m36), fmaxf(a7, a8)));
        o.w = fmaxf(m36, fmaxf(fmaxf(a7, a8), a9));
        *(float4*)&hm[r][4*c] = o;
    }
    __syncthreads();

    int cc = t & 15, ro = t >> 4;
    float4 m = *(const float4*)&hm[ro][4*cc];
#pragma unroll
    for (int d = 1; d < 7; d++) {
        float4 h = *(const float4*)&hm[ro + d][4*cc];
        m.x = fmaxf(m.x, h.x); m.y = fmaxf(m.y, h.y);
        m.z = fmaxf(m.z, h.z); m.w = fmaxf(m.w, h.w);
    }
    float4 c0 = *(const float4*)&tin[ro + 3][4*cc + 4];
    float4 o;
    o.x = (c0.x == m.x) ? c0.x : 0.f;
    o.y = (c0.y == m.y) ? c0.y : 0.f;
    o.z = (c0.z == m.z) ? c0.z : 0.f;
    o.w = (c0.w == m.w) ? c0.w : 0.f;
    *(float4*)(out + (size_t)plane * PIX + (size_t)(by + ro) * WW + bx + 4*cc) = o;
}

// ---------------- Launch ----------------
extern "C" void kernel_launch(void* const* d_in, const int* in_sizes, int n_in,
                              void* d_out, int out_size, void* d_ws, size_t ws_size,
                              hipStream_t stream) {
    const float* x = (const float*)d_in[0];
    float* O = (float*)d_out;
    float* W = (float*)d_ws;

    GW g;
    {
        double gg[7], s = 0.0;
        for (int i = 0; i < 7; i++) { double r = i - 3.0; gg[i] = exp(-r * r / 50.0); s += gg[i]; }
        for (int i = 0; i < 7; i++) g.w[i] = (float)(gg[i] / s);
    }

    zero_state<<<256, 256, 0, stream>>>();
    sobel_gauss_full<<<dim3(WW / TX, HH / TY, NIMG), 256, 0, stream>>>(x, W, g);
    select_k<<<1, 256, 0, stream>>>(0);
    hist_mid<<<SCAN_BLOCKS, 256, 0, stream>>>(W);
    select_k<<<1, 256, 0, stream>>>(1);
    hist_low<<<SCAN_BLOCKS, 256, 0, stream>>>(W);
    select_k<<<1, 256, 0, stream>>>(2);
    nms_kernel<<<dim3(WW / OX, HH / OY, PLANES), 256, 0, stream>>>(W, O);
}

// Round 19
// 492.207 us; speedup vs baseline: 1.0766x; 1.0102x over previous
//
#include <hip/hip_runtime.h>
#include <math.h>

#define HH 2048
#define WW 2048
#define NIMG 4
#define NCH 3
#define PLANES (NIMG*NCH)            // 12
#define PIX (HH*WW)                  // 4194304
#define TOT (PLANES*PIX)             // 50331648
#define W4 (WW/4)                    // 512
#define MED_RANK 25165823u           // floor(0.5*(TOT-1)), method='lower'

struct GW { float w[7]; };

// ---------------- module-global device state ----------------
// Radix split: 8 (top) / 12 (mid) / 12 (low). Lessons: (r3/r8) count, don't
// place; (r9) zero every LDS copy; (r10) >=8 loads in flight; (r6) no hot
// global addresses; (r12/r15) b128 LDS conflicts largely inherent; (r16)
// flush atomics scale with block count; (r17/r18) harness can flake — rerun
// before revising theory. r19: hists are SELF-CLEANING — select_k zeroes its
// source copies after reading (device globals zero-init at load => call 1 ok;
// stream order makes zeroing visible to next call's hist kernels).
#define H1C 64
#define H23C 16
__device__ unsigned g_hist1p[H1C * 256];
__device__ unsigned g_hist2p[H23C * 4096];
__device__ unsigned g_hist3p[H23C * 4096];
__device__ unsigned g_ctrl[8];       // [0]=b1 [1]=b2 [2]=b3 [3]=rank2 [4]=rank3
__device__ float    g_med;           // all ctrl/med rewritten every call

// ---------------- Median helpers ----------------
__device__ __forceinline__ unsigned f2key(float f) {
    unsigned b = __float_as_uint(f);
    return (b & 0x80000000u) ? ~b : (b | 0x80000000u);
}

#define HCOPY 4
#define HSTRIDE 257

// Run-length histogram accumulator [r15]: one LDS atomic per bucket-run.
struct RLE {
    unsigned cur, cnt;
    __device__ __forceinline__ void init() { cur = 0xFFFFFFFFu; cnt = 0; }
    __device__ __forceinline__ void add(unsigned* myh, unsigned b) {
        if (b == cur) { cnt++; }
        else { if (cnt) atomicAdd(&myh[cur], cnt); cur = b; cnt = 1; }
    }
    __device__ __forceinline__ void flush(unsigned* myh) {
        if (cnt) atomicAdd(&myh[cur], cnt);
    }
};

// ---------------- Megakernel: Sobel + full 7x7 Gaussian + hist0 [r16] ------
// Tile 32x32x3/block; 22.8 KB LDS (lh unioned into dead xs) -> ~7 blocks/CU.
#define TX 32
#define TY 32
__global__ __launch_bounds__(256) void sobel_gauss_full(const float* __restrict__ x,
                                                        float* __restrict__ S, GW g) {
    __shared__ float xs[40][40];        // image rows by-4..by+35; lh aliases this
    __shared__ float bh[3][38][36];     // Bh rows by-3..by+34, cols bx..bx+31
    unsigned* lh = (unsigned*)&xs[0][0];   // HCOPY*HSTRIDE = 1028 u32 <= 1600

    int bx = blockIdx.x * TX, by = blockIdx.y * TY;
    int n = blockIdx.z;
    const float* xp = x + (size_t)n * PIX;
    int t = threadIdx.x;

    // ---- stage x tile: 40 rows x 10 float4, zero-fill OOB ----
    for (int i = t; i < 40 * 10; i += 256) {
        int r = i / 10, cc = i % 10;
        int gr = by - 4 + r, gc = bx - 4 + cc * 4;
        float4 v = make_float4(0, 0, 0, 0);
        if (gr >= 0 && gr < HH && gc >= 0 && gc < WW)
            v = *(const float4*)(xp + (size_t)gr * WW + gc);
        *(float4*)&xs[r][cc * 4] = v;
    }
    __syncthreads();

    // ---- stage Bh: 38 rows x 8 col-groups, 3 channels ----
    for (int i = t; i < 38 * 8; i += 256) {
        int r = i >> 3, c = i & 7;
        int imgrow = by - 3 + r;
        if (imgrow < 0 || imgrow >= HH) {     // products zero-padded vertically
            float4 z = make_float4(0, 0, 0, 0);
            *(float4*)&bh[0][r][4 * c] = z;
            *(float4*)&bh[1][r][4 * c] = z;
            *(float4*)&bh[2][r][4 * c] = z;
            continue;
        }
        float r0[12], r1[12], r2[12];
#pragma unroll
        for (int b = 0; b < 3; b++) {
            float4 v0 = *(float4*)&xs[r][4 * c + 4 * b];
            float4 v1 = *(float4*)&xs[r + 1][4 * c + 4 * b];
            float4 v2 = *(float4*)&xs[r + 2][4 * c + 4 * b];
            r0[b*4+0]=v0.x; r0[b*4+1]=v0.y; r0[b*4+2]=v0.z; r0[b*4+3]=v0.w;
            r1[b*4+0]=v1.x; r1[b*4+1]=v1.y; r1[b*4+2]=v1.z; r1[b*4+3]=v1.w;
            r2[b*4+0]=v2.x; r2[b*4+1]=v2.y; r2[b*4+2]=v2.z; r2[b*4+3]=v2.w;
        }
        float pxx[10], pyy[10], pxy[10];
#pragma unroll
        for (int p = 0; p < 10; p++) {
            int ai = p + 1;
            int cg = bx + 4 * c - 3 + p;
            float Ix = (r0[ai+1] - r0[ai-1]) + 2.f*(r1[ai+1] - r1[ai-1]) + (r2[ai+1] - r2[ai-1]);
            float Iy = (r2[ai-1] - r0[ai-1]) + 2.f*(r2[ai]   - r0[ai])   + (r2[ai+1] - r0[ai+1]);
            bool ok = (cg >= 0 && cg < WW);
            pxx[p] = ok ? Ix * Ix : 0.f;
            pyy[p] = ok ? Iy * Iy : 0.f;
            pxy[p] = ok ? Ix * Iy : 0.f;
        }
        float4 oxx, oyy, oxy;
        float* ox = &oxx.x; float* oy = &oyy.x; float* oz = &oxy.x;
#pragma unroll
        for (int k = 0; k < 4; k++) {
            float sxx = 0.f, syy = 0.f, sxy = 0.f;
#pragma unroll
            for (int j = 0; j < 7; j++) {
                sxx += g.w[j] * pxx[k + j];
                syy += g.w[j] * pyy[k + j];
                sxy += g.w[j] * pxy[k + j];
            }
            ox[k] = sxx; oy[k] = syy; oz[k] = sxy;
        }
        *(float4*)&bh[0][r][4 * c] = oxx;
        *(float4*)&bh[1][r][4 * c] = oyy;
        *(float4*)&bh[2][r][4 * c] = oxy;
    }
    __syncthreads();

    // ---- xs now dead: zero lh (aliased) ----
    for (int i = t; i < HCOPY * HSTRIDE; i += 256) lh[i] = 0;
    __syncthreads();
    unsigned* myh = lh + (threadIdx.x & (HCOPY - 1)) * HSTRIDE;

    // ---- vertical 7-tap + S write + RLE hist: thread = 1 row x 4 cols ----
    int cg = t & 7, ro = t >> 3;              // ro in 0..31
    RLE rle; rle.init();
#pragma unroll
    for (int ch = 0; ch < 3; ch++) {
        float4 w[7];
#pragma unroll
        for (int j = 0; j < 7; j++) w[j] = *(float4*)&bh[ch][ro + j][4 * cg];
        float4 a0 = make_float4(0, 0, 0, 0);
#pragma unroll
        for (int j = 0; j < 7; j++) {
            float gw = g.w[j];
            a0.x += gw * w[j].x; a0.y += gw * w[j].y;
            a0.z += gw * w[j].z; a0.w += gw * w[j].w;
        }
        float* sp = S + (size_t)(n * NCH + ch) * PIX;
        *(float4*)(sp + (size_t)(by + ro) * WW + bx + 4 * cg) = a0;
        rle.add(myh, f2key(a0.x) >> 24); rle.add(myh, f2key(a0.y) >> 24);
        rle.add(myh, f2key(a0.z) >> 24); rle.add(myh, f2key(a0.w) >> 24);
    }
    rle.flush(myh);

    __syncthreads();
    if (threadIdx.x < 256) {
        unsigned v = 0;
#pragma unroll
        for (int c = 0; c < HCOPY; c++) v += lh[c * HSTRIDE + threadIdx.x];
        if (v) atomicAdd(&g_hist1p[((blockIdx.y * 64 + blockIdx.x) & (H1C - 1)) * 256 + threadIdx.x], v);
    }
}

// ---------------- Pass C: mid hist — 2048-block, 24-load scan [r15] --------
#define SCAN_BLOCKS 2048
#define NSTR 8
#define SLAB (TOT / 4 / NSTR)        // 1572864 float4; 3 iters x 2048 x 256
__global__ __launch_bounds__(256) void hist_mid(const float* __restrict__ S) {
    __shared__ unsigned lh[4096];
    for (int i = threadIdx.x; i < 4096; i += 256) lh[i] = 0;
    __syncthreads();
    unsigned b1 = g_ctrl[0];
    const float4* S4 = (const float4*)S;
    long long i0 = (long long)blockIdx.x * 256 + threadIdx.x;
    const long long STRIDE = (long long)SCAN_BLOCKS * 256;  // 524288
    float4 v[3][NSTR];                 // 24 loads in flight
#pragma unroll
    for (int it = 0; it < 3; it++)
#pragma unroll
        for (int s = 0; s < NSTR; s++)
            v[it][s] = S4[i0 + it * STRIDE + (long long)s * SLAB];
#pragma unroll
    for (int it = 0; it < 3; it++)
#pragma unroll
        for (int s = 0; s < NSTR; s++) {
            unsigned k0 = f2key(v[it][s].x), k1 = f2key(v[it][s].y),
                     k2 = f2key(v[it][s].z), k3 = f2key(v[it][s].w);
            if ((k0 >> 24) == b1) atomicAdd(&lh[(k0 >> 12) & 0xFFFu], 1u);
            if ((k1 >> 24) == b1) atomicAdd(&lh[(k1 >> 12) & 0xFFFu], 1u);
            if ((k2 >> 24) == b1) atomicAdd(&lh[(k2 >> 12) & 0xFFFu], 1u);
            if ((k3 >> 24) == b1) atomicAdd(&lh[(k3 >> 12) & 0xFFFu], 1u);
        }
    __syncthreads();
    unsigned cpy = (blockIdx.x & (H23C - 1)) * 4096;
    for (int i = threadIdx.x; i < 4096; i += 256) {
        unsigned vv = lh[i];
        if (vv) atomicAdd(&g_hist2p[cpy + i], vv);
    }
}

// ---------------- Pass D: low hist — 2048-block, 24-load scan [r15] --------
__global__ __launch_bounds__(256) void hist_low(const float* __restrict__ S) {
    __shared__ unsigned lh[4096];
    for (int i = threadIdx.x; i < 4096; i += 256) lh[i] = 0;
    __syncthreads();
    unsigned p2 = (g_ctrl[0] << 12) | g_ctrl[1];
    const float4* S4 = (const float4*)S;
    long long i0 = (long long)blockIdx.x * 256 + threadIdx.x;
    const long long STRIDE = (long long)SCAN_BLOCKS * 256;
    float4 v[3][NSTR];
#pragma unroll
    for (int it = 0; it < 3; it++)
#pragma unroll
        for (int s = 0; s < NSTR; s++)
            v[it][s] = S4[i0 + it * STRIDE + (long long)s * SLAB];
#pragma unroll
    for (int it = 0; it < 3; it++)
#pragma unroll
        for (int s = 0; s < NSTR; s++) {
            unsigned k0 = f2key(v[it][s].x), k1 = f2key(v[it][s].y),
                     k2 = f2key(v[it][s].z), k3 = f2key(v[it][s].w);
            if ((k0 >> 12) == p2) atomicAdd(&lh[k0 & 0xFFFu], 1u);
            if ((k1 >> 12) == p2) atomicAdd(&lh[k1 & 0xFFFu], 1u);
            if ((k2 >> 12) == p2) atomicAdd(&lh[k2 & 0xFFFu], 1u);
            if ((k3 >> 12) == p2) atomicAdd(&lh[k3 & 0xFFFu], 1u);
        }
    __syncthreads();
    unsigned cpy = (blockIdx.x & (H23C - 1)) * 4096;
    for (int i = threadIdx.x; i < 4096; i += 256) {
        unsigned vv = lh[i];
        if (vv) atomicAdd(&g_hist3p[cpy + i], vv);
    }
}

// ------- bucket select over partial hists; SELF-CLEANING (zeroes source) ---
__global__ __launch_bounds__(256) void select_k(int which) {
    __shared__ unsigned cnt[4096];
    __shared__ unsigned csum[256];
    int t = threadIdx.x;
    int nbins = (which == 0) ? 256 : 4096;
    if (which == 0) {
        unsigned s = 0;
        for (int c = 0; c < H1C; c++) {
            s += g_hist1p[c * 256 + t];
            g_hist1p[c * 256 + t] = 0;          // clean for next call
        }
        cnt[t] = s;
    } else {
        unsigned* hp = (which == 1) ? g_hist2p : g_hist3p;
        for (int i = t; i < 4096; i += 256) {
            unsigned s = 0;
            for (int c = 0; c < H23C; c++) {
                s += hp[c * 4096 + i];
                hp[c * 4096 + i] = 0;           // clean for next call
            }
            cnt[i] = s;
        }
    }
    __syncthreads();
    int per = nbins >> 8;
    unsigned s = 0;
    for (int j = 0; j < per; j++) s += cnt[t * per + j];
    csum[t] = s;
    __syncthreads();
    if (t == 0) {
        unsigned r = (which == 0) ? MED_RANK : (which == 1) ? g_ctrl[3] : g_ctrl[4];
        unsigned acc = 0; int c = 0;
        for (; c < 256; c++) { if (acc + csum[c] > r) break; acc += csum[c]; }
        int b = c * per;
        for (;; b++) { if (acc + cnt[b] > r) break; acc += cnt[b]; }
        if (which == 0)      { g_ctrl[0] = (unsigned)b; g_ctrl[3] = r - acc; }
        else if (which == 1) { g_ctrl[1] = (unsigned)b; g_ctrl[4] = r - acc; }
        else {
            g_ctrl[2] = (unsigned)b;
            unsigned key = (g_ctrl[0] << 24) | (g_ctrl[1] << 12) | (unsigned)b;
            unsigned bits = (key & 0x80000000u) ? (key ^ 0x80000000u) : ~key;
            g_med = __uint_as_float(bits);
        }
    }
}

// ---------------- Pass H: threshold + 7x7 NMS + mask — 64x32 tile ----------
#define OX 64
#define OY 32
__global__ __launch_bounds__(256) void nms_kernel(const float* __restrict__ S,
                                                  float* __restrict__ out) {
    __shared__ float tin[38][72];     // rows by-3..by+34, cols bx-4..bx+67
    __shared__ float hm[38][68];
    float med = g_med;
    int plane = blockIdx.z;
    int bx = blockIdx.x * OX, by = blockIdx.y * OY;
    const float* Sp = S + (size_t)plane * PIX;
    int t = threadIdx.x;

    for (int i = t; i < 38 * 18; i += 256) {
        int r = i / 18, cc = i % 18;
        int ghh = by + r - 3;
        int gc  = bx - 4 + cc * 4;
        float4 v = make_float4(-INFINITY, -INFINITY, -INFINITY, -INFINITY);
        if (ghh >= 0 && ghh < HH && gc >= 0 && gc < WW) {
            float4 s = *(const float4*)(Sp + (size_t)ghh * WW + gc);
            v.x = (s.x > med) ? s.x : 0.f;
            v.y = (s.y > med) ? s.y : 0.f;
            v.z = (s.z > med) ? s.z : 0.f;
            v.w = (s.w > med) ? s.w : 0.f;
        }
        *(float4*)&tin[r][cc * 4] = v;
    }
    __syncthreads();

    for (int i = t; i < 38 * 16; i += 256) {
        int r = i / 16, c = i % 16;
        float a0 = tin[r][4*c+1], a1 = tin[r][4*c+2], a2 = tin[r][4*c+3];
        float a3 = tin[r][4*c+4], a4 = tin[r][4*c+5], a5 = tin[r][4*c+6];
        float a6 = tin[r][4*c+7], a7 = tin[r][4*c+8], a8 = tin[r][4*c+9];
        float a9 = tin[r][4*c+10];
        float m03 = fmaxf(fmaxf(a0, a1), fmaxf(a2, a3));
        float m36 = fmaxf(fmaxf(a3, a4), fmaxf(a5, a6));
        float4 o;
        o.x = fmaxf(m03, fmaxf(fmaxf(a4, a5), a6));
        o.y = fmaxf(fmaxf(a1, a2), fmaxf(m36, a7));
        o.z = fmaxf(fmaxf(a2, a3), fmaxf(fmaxf(a4, m36), fmaxf(a7, a8)));
        o.w = fmaxf(m36, fmaxf(fmaxf(a7, a8), a9));
        *(float4*)&hm[r][4*c] = o;
    }
    __syncthreads();

    int cc = t & 15, r0 = t >> 4;             // r0 in 0..15; rows r0, r0+16
#pragma unroll
    for (int half = 0; half < 2; half++) {
        int ro = r0 + half * 16;
        float4 m = *(const float4*)&hm[ro][4*cc];
#pragma unroll
        for (int d = 1; d < 7; d++) {
            float4 h = *(const float4*)&hm[ro + d][4*cc];
            m.x = fmaxf(m.x, h.x); m.y = fmaxf(m.y, h.y);
            m.z = fmaxf(m.z, h.z); m.w = fmaxf(m.w, h.w);
        }
        float4 c0 = *(const float4*)&tin[ro + 3][4*cc + 4];
        float4 o;
        o.x = (c0.x == m.x) ? c0.x : 0.f;
        o.y = (c0.y == m.y) ? c0.y : 0.f;
        o.z = (c0.z == m.z) ? c0.z : 0.f;
        o.w = (c0.w == m.w) ? c0.w : 0.f;
        *(float4*)(out + (size_t)plane * PIX + (size_t)(by + ro) * WW + bx + 4*cc) = o;
    }
}

// ---------------- Launch ----------------
extern "C" void kernel_launch(void* const* d_in, const int* in_sizes, int n_in,
                              void* d_out, int out_size, void* d_ws, size_t ws_size,
                              hipStream_t stream) {
    const float* x = (const float*)d_in[0];
    float* O = (float*)d_out;
    float* W = (float*)d_ws;

    GW g;
    {
        double gg[7], s = 0.0;
        for (int i = 0; i < 7; i++) { double r = i - 3.0; gg[i] = exp(-r * r / 50.0); s += gg[i]; }
        for (int i = 0; i < 7; i++) g.w[i] = (float)(gg[i] / s);
    }

    // no zero_state: hists are self-cleaned by select_k; ctrl/med rewritten
    sobel_gauss_full<<<dim3(WW / TX, HH / TY, NIMG), 256, 0, stream>>>(x, W, g);
    select_k<<<1, 256, 0, stream>>>(0);
    hist_mid<<<SCAN_BLOCKS, 256, 0, stream>>>(W);
    select_k<<<1, 256, 0, stream>>>(1);
    hist_low<<<SCAN_BLOCKS, 256, 0, stream>>>(W);
    select_k<<<1, 256, 0, stream>>>(2);
    nms_kernel<<<dim3(WW / OX, HH / OY, PLANES), 256, 0, stream>>>(W, O);
}